// Round 10
// baseline (310.425 us; speedup 1.0000x reference)
//
#include <hip/hip_runtime.h>
#include <hip/hip_cooperative_groups.h>

namespace cg = cooperative_groups;

#define HID 256
#define LK  2048
#define LQ  64
#define BSZ 8
#define M   16
#define NKEY (BSZ * M)        // 128
#define SPLIT 32              // key chunks per n
#define CHUNKS (NKEY * SPLIT) // 4096 chunks of 64 rows (64 KB) each
#define ROWS (LK / SPLIT)     // 64
#define RPW (ROWS / 4)        // 16 rows per wave

using f32x4 = __attribute__((ext_vector_type(4))) float;

// ===========================================================================
// Fused cooperative kernel, ONE grid.sync (R7 had two):
//  - att[128] + flag zeroed by a hipMemsetAsync node before the kernel.
//  - Last 8 blocks compute u[qb] FIRST, then release-add flag (agent scope).
//  - All blocks stream their chunks; right before the FIRST per-chunk dot
//    (~30us into the kernel) they acquire-spin on flag>=8 — free in steady
//    state. Per chunk: csum (registers) -> dot u -> one atomicAdd(att[n]).
//  - grid.sync()  (the only barrier: att complete before argmax)
//  - argmax in LDS + grid-stride gather copy.
// ===========================================================================
__global__ __launch_bounds__(256)
void fused_kernel(const float* __restrict__ query,
                  const float* __restrict__ key,
                  const float* __restrict__ w_q,
                  const float* __restrict__ b_q,
                  const float* __restrict__ w_k,
                  float* __restrict__ u,
                  float* __restrict__ att,
                  int* __restrict__ flag,
                  float* __restrict__ out,
                  int nb) {
    cg::grid_group grid = cg::this_grid();
    const int bid  = blockIdx.x;
    const int t    = threadIdx.x;
    const int wave = t >> 6;
    const int lane = t & 63;

    __shared__ float lds[4][HID];
    __shared__ float wp[4];

    // ---- u-blocks: compute u FIRST, then signal ----
    if (bid >= nb - BSZ) {
        const int qb = bid - (nb - BSZ);
        __shared__ float qs[HID];
        __shared__ float qsv[HID];
        const float* qbase = query + (size_t)qb * LQ * HID;

        float4 a = make_float4(0.f, 0.f, 0.f, 0.f);
#pragma unroll
        for (int r = 0; r < LQ / 4; ++r) {
            float4 v = ((const float4*)(qbase + (size_t)(wave * (LQ / 4) + r) * HID))[lane];
            a.x += v.x; a.y += v.y; a.z += v.z; a.w += v.w;
        }
        ((float4*)lds[wave])[lane] = a;
        __syncthreads();
        qs[t] = (lds[0][t] + lds[1][t]) + (lds[2][t] + lds[3][t]);
        __syncthreads();

        const float4* wrow = (const float4*)(w_q + (size_t)t * HID);
        float acc = 0.f;
#pragma unroll
        for (int h4 = 0; h4 < HID / 4; ++h4) {
            float4 w = wrow[h4];
            acc += w.x * qs[h4 * 4 + 0] + w.y * qs[h4 * 4 + 1]
                 + w.z * qs[h4 * 4 + 2] + w.w * qs[h4 * 4 + 3];
        }
        qsv[t] = acc + (float)LQ * b_q[t];
        __syncthreads();

        float4 ua = make_float4(0.f, 0.f, 0.f, 0.f);
#pragma unroll 8
        for (int i = 0; i < 64; ++i) {
            const int o = wave * 64 + i;
            float4 w = ((const float4*)(w_k + (size_t)o * HID))[lane];
            const float q = qsv[o];
            ua.x += q * w.x; ua.y += q * w.y; ua.z += q * w.z; ua.w += q * w.w;
        }
        ((float4*)lds[wave])[lane] = ua;
        __syncthreads();
        u[(size_t)qb * HID + t] = (lds[0][t] + lds[1][t]) + (lds[2][t] + lds[3][t]);
        __syncthreads();   // all 256 u-stores complete (vmcnt drained) before signal
        if (t == 0)
            __hip_atomic_fetch_add(flag, 1, __ATOMIC_RELEASE,
                                   __HIP_MEMORY_SCOPE_AGENT);
        __syncthreads();
    }

    // ---- streaming chunks: csum -> (first time: wait u) -> dot -> atomic ----
    bool uReady = false;
    for (int c = bid; c < CHUNKS; c += nb) {
        const int n  = c >> 5;              // /SPLIT
        const int ch = c & (SPLIT - 1);
        const f32x4* base = (const f32x4*)(key + (size_t)n * LK * HID
                                               + (size_t)ch * ROWS * HID);
        const int r0 = wave * RPW;

        f32x4 a0 = {0.f, 0.f, 0.f, 0.f};
        f32x4 a1 = {0.f, 0.f, 0.f, 0.f};
        f32x4 a2 = {0.f, 0.f, 0.f, 0.f};
        f32x4 a3 = {0.f, 0.f, 0.f, 0.f};
#pragma unroll 4
        for (int i = 0; i < RPW; i += 4) {
            f32x4 v0 = __builtin_nontemporal_load(base + (size_t)(r0 + i + 0) * (HID / 4) + lane);
            f32x4 v1 = __builtin_nontemporal_load(base + (size_t)(r0 + i + 1) * (HID / 4) + lane);
            f32x4 v2 = __builtin_nontemporal_load(base + (size_t)(r0 + i + 2) * (HID / 4) + lane);
            f32x4 v3 = __builtin_nontemporal_load(base + (size_t)(r0 + i + 3) * (HID / 4) + lane);
            a0 += v0; a1 += v1; a2 += v2; a3 += v3;
        }
        a0 = (a0 + a1) + (a2 + a3);

        ((f32x4*)lds[wave])[lane] = a0;
        __syncthreads();                       // lds csum ready
        const float cs = (lds[0][t] + lds[1][t]) + (lds[2][t] + lds[3][t]);

        if (!uReady) {                          // block-uniform branch
            if (t == 0)
                while (__hip_atomic_load(flag, __ATOMIC_ACQUIRE,
                                         __HIP_MEMORY_SCOPE_AGENT) < BSZ) {}
            __syncthreads();                    // u visible to whole block
            uReady = true;
        }

        const int b = n >> 4;                   // /M
        float v = cs * u[(size_t)b * HID + t];
        for (int off = 32; off; off >>= 1) v += __shfl_down(v, off);
        if (lane == 0) wp[wave] = v;
        __syncthreads();                        // wp ready; lds reads done
        if (t == 0) atomicAdd(&att[n], (wp[0] + wp[1]) + (wp[2] + wp[3]));
        __syncthreads();                        // t0's wp read before next write
    }

    grid.sync();   // att complete

    // ---- argmax + gather ----
    __shared__ float satt[NKEY];
    __shared__ int   sbest[BSZ];
    if (t < NKEY) satt[t] = att[t];
    __syncthreads();
    if (t < BSZ) {
        const float* a = satt + t * M;
        int best = 0;
        float bv = a[0];
        for (int m = 1; m < M; ++m)
            if (a[m] > bv) { bv = a[m]; best = m; }  // strict >: first-max
        sbest[t] = best;
    }
    __syncthreads();

    const size_t total = (size_t)BSZ * LK * HID / 4;   // 1,048,576 float4s
    const f32x4* key4 = (const f32x4*)key;
    f32x4* out4 = (f32x4*)out;
    for (size_t i = (size_t)bid * blockDim.x + t; i < total;
         i += (size_t)nb * blockDim.x) {
        const int b = (int)(i >> 17);                  // per_b = 2^17 float4s
        const size_t off = i & (size_t)131071;
        const size_t n = (size_t)(b * M + sbest[b]);
        f32x4 val = __builtin_nontemporal_load(key4 + ((n << 17) | off));
        __builtin_nontemporal_store(val, out4 + i);
    }
}

// ======================= fallback: proven R4 3-kernel path ==================
__global__ void colsum_kernel(const float* __restrict__ query,
                              const float* __restrict__ key,
                              const float* __restrict__ w_q,
                              const float* __restrict__ b_q,
                              const float* __restrict__ w_k,
                              float* __restrict__ partial,
                              float* __restrict__ u,
                              unsigned long long* __restrict__ amax) {
    const int bid  = blockIdx.x;
    const int t    = threadIdx.x;
    const int wave = t >> 6;
    const int lane = t & 63;

    if (bid < BSZ) {
        if (t == 0) amax[bid] = 0ull;
        __shared__ float qs[HID];
        __shared__ float qsv[HID];
        const float* qbase = query + (size_t)bid * LQ * HID;
        float s = 0.f;
        for (int r = 0; r < LQ; ++r) s += qbase[(size_t)r * HID + t];
        qs[t] = s;
        __syncthreads();
        const float4* wrow = (const float4*)(w_q + (size_t)t * HID);
        float acc = 0.f;
#pragma unroll 8
        for (int h4 = 0; h4 < HID / 4; ++h4) {
            float4 w = wrow[h4];
            acc += w.x * qs[h4 * 4 + 0] + w.y * qs[h4 * 4 + 1]
                 + w.z * qs[h4 * 4 + 2] + w.w * qs[h4 * 4 + 3];
        }
        qsv[t] = acc + (float)LQ * b_q[t];
        __syncthreads();
        float uh = 0.f;
#pragma unroll 4
        for (int o = 0; o < HID; ++o) uh += qsv[o] * w_k[(size_t)o * HID + t];
        u[(size_t)bid * HID + t] = uh;
    } else {
        const int kb = bid - BSZ;
        const int n  = kb >> 5;
        const int ch = kb & (SPLIT - 1);
        const float* base = key + (size_t)n * LK * HID + (size_t)ch * ROWS * HID;
        const int r0 = wave * RPW;
        float4 a0 = make_float4(0.f, 0.f, 0.f, 0.f);
        float4 a1 = make_float4(0.f, 0.f, 0.f, 0.f);
        float4 a2 = make_float4(0.f, 0.f, 0.f, 0.f);
        float4 a3 = make_float4(0.f, 0.f, 0.f, 0.f);
#pragma unroll 4
        for (int i = 0; i < RPW; i += 4) {
            float4 v0 = ((const float4*)(base + (size_t)(r0 + i + 0) * HID))[lane];
            float4 v1 = ((const float4*)(base + (size_t)(r0 + i + 1) * HID))[lane];
            float4 v2 = ((const float4*)(base + (size_t)(r0 + i + 2) * HID))[lane];
            float4 v3 = ((const float4*)(base + (size_t)(r0 + i + 3) * HID))[lane];
            a0.x += v0.x; a0.y += v0.y; a0.z += v0.z; a0.w += v0.w;
            a1.x += v1.x; a1.y += v1.y; a1.z += v1.z; a1.w += v1.w;
            a2.x += v2.x; a2.y += v2.y; a2.z += v2.z; a2.w += v2.w;
            a3.x += v3.x; a3.y += v3.y; a3.z += v3.z; a3.w += v3.w;
        }
        a0.x = (a0.x + a1.x) + (a2.x + a3.x);
        a0.y = (a0.y + a1.y) + (a2.y + a3.y);
        a0.z = (a0.z + a1.z) + (a2.z + a3.z);
        a0.w = (a0.w + a1.w) + (a2.w + a3.w);
        __shared__ float klds[4][HID];
        ((float4*)klds[wave])[lane] = a0;
        __syncthreads();
        partial[(size_t)kb * HID + t] =
            (klds[0][t] + klds[1][t]) + (klds[2][t] + klds[3][t]);
    }
}

__global__ void att_kernel(const float* __restrict__ partial,
                           const float* __restrict__ u,
                           unsigned long long* __restrict__ amax) {
    const int n    = blockIdx.x;
    const int b    = n >> 4;
    const int m    = n & (M - 1);
    const int t    = threadIdx.x;
    const int wave = t >> 6;
    const int lane = t & 63;

    const float* p = partial + (size_t)n * SPLIT * HID + t;
    float s0 = 0.f, s1 = 0.f, s2 = 0.f, s3 = 0.f;
#pragma unroll
    for (int c = 0; c < SPLIT; c += 4) {
        s0 += p[(size_t)(c + 0) * HID];
        s1 += p[(size_t)(c + 1) * HID];
        s2 += p[(size_t)(c + 2) * HID];
        s3 += p[(size_t)(c + 3) * HID];
    }
    float v = ((s0 + s1) + (s2 + s3)) * u[(size_t)b * HID + t];
    for (int off = 32; off; off >>= 1) v += __shfl_down(v, off);
    __shared__ float wp[4];
    if (lane == 0) wp[wave] = v;
    __syncthreads();
    if (t == 0) {
        float att = (wp[0] + wp[1]) + (wp[2] + wp[3]);
        unsigned int fb = __float_as_uint(att);
        unsigned int mono = (fb & 0x80000000u) ? ~fb : (fb | 0x80000000u);
        unsigned long long pack =
            ((unsigned long long)mono << 32) | (unsigned int)(M - 1 - m);
        atomicMax(&amax[b], pack);
    }
}

__global__ void gather_kernel(const float* __restrict__ key,
                              const unsigned long long* __restrict__ amax,
                              float* __restrict__ out) {
    const int b = blockIdx.y;
    const unsigned long long v = amax[b];
    const int m = M - 1 - (int)(v & 0xFFFFFFFFu);
    const int n = b * M + m;
    const size_t per_b = (size_t)LK * HID / 4;
    const size_t off = (size_t)blockIdx.x * blockDim.x + threadIdx.x;
    ((float4*)out)[(size_t)b * per_b + off] =
        ((const float4*)key)[(size_t)n * per_b + off];
}

extern "C" void kernel_launch(void* const* d_in, const int* in_sizes, int n_in,
                              void* d_out, int out_size, void* d_ws, size_t ws_size,
                              hipStream_t stream) {
    const float* query = (const float*)d_in[0];
    const float* key   = (const float*)d_in[1];
    const float* w_q   = (const float*)d_in[2];
    const float* b_q   = (const float*)d_in[3];
    const float* w_k   = (const float*)d_in[4];
    float* out = (float*)d_out;

    // ws layout (floats): att[0,128) | flag@128 | pad | amax(u64x8)@132 |
    //                     u@[148,2196) | partial@[2196,...) (fallback only)
    float* ws = (float*)d_ws;
    float* att  = ws;
    int*   flag = (int*)(ws + 128);
    unsigned long long* amax = (unsigned long long*)(ws + 132);
    float* u       = ws + 148;
    float* partial = ws + 2196;

    // Zero att + flag before the kernel (memset node; capture-safe).
    hipMemsetAsync(d_ws, 0, 132 * sizeof(float), stream);

    int coop = 0;
    hipDeviceGetAttribute(&coop, hipDeviceAttributeCooperativeLaunch, 0);

    bool launched = false;
    if (coop) {
        int maxActive = 0;
        hipError_t oe = hipOccupancyMaxActiveBlocksPerMultiprocessor(
            &maxActive, (const void*)fused_kernel, 256, 0);
        int ncu = 0;
        hipDeviceGetAttribute(&ncu, hipDeviceAttributeMultiprocessorCount, 0);
        if (oe == hipSuccess && maxActive >= 1 && ncu >= 1) {
            long long cap = (long long)ncu * maxActive;  // strict co-residency
            int nb = (int)(cap > 2048 ? 2048 : cap);
            if (nb >= 64) {
                void* args[] = {(void*)&query, (void*)&key, (void*)&w_q,
                                (void*)&b_q,   (void*)&w_k, (void*)&u,
                                (void*)&att,   (void*)&flag, (void*)&out,
                                (void*)&nb};
                hipError_t le = hipLaunchCooperativeKernel(
                    (const void*)fused_kernel, dim3(nb), dim3(256), args, 0,
                    stream);
                launched = (le == hipSuccess);
            }
        }
    }

    if (!launched) {
        hipLaunchKernelGGL(colsum_kernel, dim3(BSZ + CHUNKS), dim3(256), 0,
                           stream, query, key, w_q, b_q, w_k, partial, u, amax);
        hipLaunchKernelGGL(att_kernel, dim3(NKEY), dim3(256), 0, stream,
                           partial, u, amax);
        hipLaunchKernelGGL(gather_kernel, dim3(512, BSZ), dim3(256), 0, stream,
                           key, amax, out);
    }
}

// Round 11
// 69.180 us; speedup vs baseline: 4.4872x; 4.4872x over previous
//
#include <hip/hip_runtime.h>
#include <hip/hip_cooperative_groups.h>

namespace cg = cooperative_groups;

#define HID 256
#define LK  2048
#define LQ  64
#define BSZ 8
#define M   16
#define NKEY (BSZ * M)        // 128
#define SPLIT 32              // key chunks per n
#define CHUNKS (NKEY * SPLIT) // 4096 chunks of 64 rows (64 KB) each
#define ROWS (LK / SPLIT)     // 64
#define RPW (ROWS / 4)        // 16 rows per wave
#define MAXC 4                // max chunks per block (nb >= 1024 guaranteed)

using f32x4 = __attribute__((ext_vector_type(4))) float;

// ===========================================================================
// R8 structure (best: 69.1 us) with ONE change: phase-A key loads are
// inline-asm global_load_dwordx4 with sc0 sc1 nt cache-policy bits to
// demote L2/L3 caching of the read-once 256MB stream (key == L3 capacity;
// R7/R8 counters show 50% L3 absorption yet only ~4.4 TB/s — allocate/evict
// churn suspected). Explicit vmcnt(0) + sched_barrier(0) per guide rule #18;
// named v0..v7 regs per rule #20.
// ===========================================================================
__global__ __launch_bounds__(256)
void fused_kernel(const float* __restrict__ query,
                  const float* __restrict__ key,
                  const float* __restrict__ w_q,
                  const float* __restrict__ b_q,
                  const float* __restrict__ w_k,
                  float* __restrict__ u,
                  float* __restrict__ att,
                  float* __restrict__ out,
                  int nb) {
    cg::grid_group grid = cg::this_grid();
    const int bid  = blockIdx.x;
    const int t    = threadIdx.x;
    const int wave = t >> 6;
    const int lane = t & 63;

    __shared__ float lds[4][HID];
    __shared__ float wp[4];

    // ---------------- Phase A ----------------
    if (bid == 0 && t < NKEY) att[t] = 0.f;   // ws not re-poisoned: zero per call

    float csum[MAXC];
    int   ccid[MAXC];
    int   nc = 0;
    for (int c = bid; c < CHUNKS; c += nb) {
        const int n  = c >> 5;              // /SPLIT
        const int ch = c & (SPLIT - 1);
        const f32x4* base = (const f32x4*)(key + (size_t)n * LK * HID
                                               + (size_t)ch * ROWS * HID);
        const int r0 = wave * RPW;
        const f32x4* p = base + (size_t)r0 * (HID / 4) + lane;

        f32x4 a0 = {0.f, 0.f, 0.f, 0.f};
        f32x4 a1 = {0.f, 0.f, 0.f, 0.f};
        f32x4 a2 = {0.f, 0.f, 0.f, 0.f};
        f32x4 a3 = {0.f, 0.f, 0.f, 0.f};
#pragma unroll
        for (int half = 0; half < 2; ++half) {
            const f32x4* q = p + (size_t)(half * 8) * (HID / 4);
            f32x4 v0, v1, v2, v3, v4, v5, v6, v7;
            asm volatile("global_load_dwordx4 %0, %1, off sc0 sc1 nt"
                         : "=v"(v0) : "v"(q + 0 * (HID / 4)));
            asm volatile("global_load_dwordx4 %0, %1, off sc0 sc1 nt"
                         : "=v"(v1) : "v"(q + 1 * (HID / 4)));
            asm volatile("global_load_dwordx4 %0, %1, off sc0 sc1 nt"
                         : "=v"(v2) : "v"(q + 2 * (HID / 4)));
            asm volatile("global_load_dwordx4 %0, %1, off sc0 sc1 nt"
                         : "=v"(v3) : "v"(q + 3 * (HID / 4)));
            asm volatile("global_load_dwordx4 %0, %1, off sc0 sc1 nt"
                         : "=v"(v4) : "v"(q + 4 * (HID / 4)));
            asm volatile("global_load_dwordx4 %0, %1, off sc0 sc1 nt"
                         : "=v"(v5) : "v"(q + 5 * (HID / 4)));
            asm volatile("global_load_dwordx4 %0, %1, off sc0 sc1 nt"
                         : "=v"(v6) : "v"(q + 6 * (HID / 4)));
            asm volatile("global_load_dwordx4 %0, %1, off sc0 sc1 nt"
                         : "=v"(v7) : "v"(q + 7 * (HID / 4)));
            asm volatile("s_waitcnt vmcnt(0)" ::: "memory");
            __builtin_amdgcn_sched_barrier(0);
            a0 += v0; a1 += v1; a2 += v2; a3 += v3;
            a0 += v4; a1 += v5; a2 += v6; a3 += v7;
        }
        a0 = (a0 + a1) + (a2 + a3);

        ((f32x4*)lds[wave])[lane] = a0;
        __syncthreads();
        csum[nc] = (lds[0][t] + lds[1][t]) + (lds[2][t] + lds[3][t]);
        ccid[nc] = c;
        ++nc;
        __syncthreads();   // lds reused next chunk / by query path
    }

    if (bid >= nb - BSZ) {
        // ---- query path -> u[qb] (R5-proven wave-split + LDS reduce) ----
        const int qb = bid - (nb - BSZ);
        __shared__ float qs[HID];
        __shared__ float qsv[HID];
        const float* qbase = query + (size_t)qb * LQ * HID;

        float4 a = make_float4(0.f, 0.f, 0.f, 0.f);
#pragma unroll
        for (int r = 0; r < LQ / 4; ++r) {
            float4 v = ((const float4*)(qbase + (size_t)(wave * (LQ / 4) + r) * HID))[lane];
            a.x += v.x; a.y += v.y; a.z += v.z; a.w += v.w;
        }
        ((float4*)lds[wave])[lane] = a;
        __syncthreads();
        qs[t] = (lds[0][t] + lds[1][t]) + (lds[2][t] + lds[3][t]);
        __syncthreads();

        const float4* wrow = (const float4*)(w_q + (size_t)t * HID);
        float acc = 0.f;
#pragma unroll
        for (int h4 = 0; h4 < HID / 4; ++h4) {
            float4 w = wrow[h4];
            acc += w.x * qs[h4 * 4 + 0] + w.y * qs[h4 * 4 + 1]
                 + w.z * qs[h4 * 4 + 2] + w.w * qs[h4 * 4 + 3];
        }
        qsv[t] = acc + (float)LQ * b_q[t];
        __syncthreads();

        float4 ua = make_float4(0.f, 0.f, 0.f, 0.f);
#pragma unroll 8
        for (int i = 0; i < 64; ++i) {
            const int o = wave * 64 + i;
            float4 w = ((const float4*)(w_k + (size_t)o * HID))[lane];
            const float q = qsv[o];
            ua.x += q * w.x; ua.y += q * w.y; ua.z += q * w.z; ua.w += q * w.w;
        }
        ((float4*)lds[wave])[lane] = ua;
        __syncthreads();
        u[(size_t)qb * HID + t] = (lds[0][t] + lds[1][t]) + (lds[2][t] + lds[3][t]);
    }

    grid.sync();

    // ---------------- Phase B: register chunk-sums . u -> att atomics ------
    for (int i = 0; i < nc; ++i) {
        const int n = ccid[i] >> 5;     // /SPLIT
        const int b = n >> 4;           // /M
        float v = csum[i] * u[(size_t)b * HID + t];
        for (int off = 32; off; off >>= 1) v += __shfl_down(v, off);
        if (lane == 0) wp[wave] = v;
        __syncthreads();
        if (t == 0) atomicAdd(&att[n], (wp[0] + wp[1]) + (wp[2] + wp[3]));
        __syncthreads();   // wp reused next i
    }

    grid.sync();

    // ---------------- Phase C: per-block argmax + gather -------------------
    __shared__ float satt[NKEY];
    __shared__ int   sbest[BSZ];
    if (t < NKEY) satt[t] = att[t];
    __syncthreads();
    if (t < BSZ) {
        const float* a = satt + t * M;
        int best = 0;
        float bv = a[0];
        for (int m = 1; m < M; ++m)
            if (a[m] > bv) { bv = a[m]; best = m; }  // strict >: first-max
        sbest[t] = best;
    }
    __syncthreads();

    const size_t total = (size_t)BSZ * LK * HID / 4;   // 1,048,576 float4s
    const f32x4* key4 = (const f32x4*)key;
    f32x4* out4 = (f32x4*)out;
    for (size_t i = (size_t)bid * blockDim.x + t; i < total;
         i += (size_t)nb * blockDim.x) {
        const int b = (int)(i >> 17);                  // per_b = 2^17 float4s
        const size_t off = i & (size_t)131071;
        const size_t n = (size_t)(b * M + sbest[b]);
        f32x4 val = __builtin_nontemporal_load(key4 + ((n << 17) | off));
        __builtin_nontemporal_store(val, out4 + i);
    }
}

// ======================= fallback: proven R4 3-kernel path ==================
__global__ void colsum_kernel(const float* __restrict__ query,
                              const float* __restrict__ key,
                              const float* __restrict__ w_q,
                              const float* __restrict__ b_q,
                              const float* __restrict__ w_k,
                              float* __restrict__ partial,
                              float* __restrict__ u,
                              unsigned long long* __restrict__ amax) {
    const int bid  = blockIdx.x;
    const int t    = threadIdx.x;
    const int wave = t >> 6;
    const int lane = t & 63;

    if (bid < BSZ) {
        if (t == 0) amax[bid] = 0ull;
        __shared__ float qs[HID];
        __shared__ float qsv[HID];
        const float* qbase = query + (size_t)bid * LQ * HID;
        float s = 0.f;
        for (int r = 0; r < LQ; ++r) s += qbase[(size_t)r * HID + t];
        qs[t] = s;
        __syncthreads();
        const float4* wrow = (const float4*)(w_q + (size_t)t * HID);
        float acc = 0.f;
#pragma unroll 8
        for (int h4 = 0; h4 < HID / 4; ++h4) {
            float4 w = wrow[h4];
            acc += w.x * qs[h4 * 4 + 0] + w.y * qs[h4 * 4 + 1]
                 + w.z * qs[h4 * 4 + 2] + w.w * qs[h4 * 4 + 3];
        }
        qsv[t] = acc + (float)LQ * b_q[t];
        __syncthreads();
        float uh = 0.f;
#pragma unroll 4
        for (int o = 0; o < HID; ++o) uh += qsv[o] * w_k[(size_t)o * HID + t];
        u[(size_t)bid * HID + t] = uh;
    } else {
        const int kb = bid - BSZ;
        const int n  = kb >> 5;
        const int ch = kb & (SPLIT - 1);
        const float* base = key + (size_t)n * LK * HID + (size_t)ch * ROWS * HID;
        const int r0 = wave * RPW;
        float4 a0 = make_float4(0.f, 0.f, 0.f, 0.f);
        float4 a1 = make_float4(0.f, 0.f, 0.f, 0.f);
        float4 a2 = make_float4(0.f, 0.f, 0.f, 0.f);
        float4 a3 = make_float4(0.f, 0.f, 0.f, 0.f);
#pragma unroll 4
        for (int i = 0; i < RPW; i += 4) {
            float4 v0 = ((const float4*)(base + (size_t)(r0 + i + 0) * HID))[lane];
            float4 v1 = ((const float4*)(base + (size_t)(r0 + i + 1) * HID))[lane];
            float4 v2 = ((const float4*)(base + (size_t)(r0 + i + 2) * HID))[lane];
            float4 v3 = ((const float4*)(base + (size_t)(r0 + i + 3) * HID))[lane];
            a0.x += v0.x; a0.y += v0.y; a0.z += v0.z; a0.w += v0.w;
            a1.x += v1.x; a1.y += v1.y; a1.z += v1.z; a1.w += v1.w;
            a2.x += v2.x; a2.y += v2.y; a2.z += v2.z; a2.w += v2.w;
            a3.x += v3.x; a3.y += v3.y; a3.z += v3.z; a3.w += v3.w;
        }
        a0.x = (a0.x + a1.x) + (a2.x + a3.x);
        a0.y = (a0.y + a1.y) + (a2.y + a3.y);
        a0.z = (a0.z + a1.z) + (a2.z + a3.z);
        a0.w = (a0.w + a1.w) + (a2.w + a3.w);
        __shared__ float klds[4][HID];
        ((float4*)klds[wave])[lane] = a0;
        __syncthreads();
        partial[(size_t)kb * HID + t] =
            (klds[0][t] + klds[1][t]) + (klds[2][t] + klds[3][t]);
    }
}

__global__ void att_kernel(const float* __restrict__ partial,
                           const float* __restrict__ u,
                           unsigned long long* __restrict__ amax) {
    const int n    = blockIdx.x;
    const int b    = n >> 4;
    const int m    = n & (M - 1);
    const int t    = threadIdx.x;
    const int wave = t >> 6;
    const int lane = t & 63;

    const float* p = partial + (size_t)n * SPLIT * HID + t;
    float s0 = 0.f, s1 = 0.f, s2 = 0.f, s3 = 0.f;
#pragma unroll
    for (int c = 0; c < SPLIT; c += 4) {
        s0 += p[(size_t)(c + 0) * HID];
        s1 += p[(size_t)(c + 1) * HID];
        s2 += p[(size_t)(c + 2) * HID];
        s3 += p[(size_t)(c + 3) * HID];
    }
    float v = ((s0 + s1) + (s2 + s3)) * u[(size_t)b * HID + t];
    for (int off = 32; off; off >>= 1) v += __shfl_down(v, off);
    __shared__ float wp[4];
    if (lane == 0) wp[wave] = v;
    __syncthreads();
    if (t == 0) {
        float att = (wp[0] + wp[1]) + (wp[2] + wp[3]);
        unsigned int fb = __float_as_uint(att);
        unsigned int mono = (fb & 0x80000000u) ? ~fb : (fb | 0x80000000u);
        unsigned long long pack =
            ((unsigned long long)mono << 32) | (unsigned int)(M - 1 - m);
        atomicMax(&amax[b], pack);
    }
}

__global__ void gather_kernel(const float* __restrict__ key,
                              const unsigned long long* __restrict__ amax,
                              float* __restrict__ out) {
    const int b = blockIdx.y;
    const unsigned long long v = amax[b];
    const int m = M - 1 - (int)(v & 0xFFFFFFFFu);
    const int n = b * M + m;
    const size_t per_b = (size_t)LK * HID / 4;
    const size_t off = (size_t)blockIdx.x * blockDim.x + threadIdx.x;
    ((float4*)out)[(size_t)b * per_b + off] =
        ((const float4*)key)[(size_t)n * per_b + off];
}

extern "C" void kernel_launch(void* const* d_in, const int* in_sizes, int n_in,
                              void* d_out, int out_size, void* d_ws, size_t ws_size,
                              hipStream_t stream) {
    const float* query = (const float*)d_in[0];
    const float* key   = (const float*)d_in[1];
    const float* w_q   = (const float*)d_in[2];
    const float* b_q   = (const float*)d_in[3];
    const float* w_k   = (const float*)d_in[4];
    float* out = (float*)d_out;

    // ws layout (shared by both paths): amax | att | u | partial
    unsigned long long* amax = (unsigned long long*)d_ws;
    float* att     = (float*)(amax + BSZ);
    float* u       = att + NKEY;
    float* partial = u + (size_t)BSZ * HID;

    int coop = 0;
    hipDeviceGetAttribute(&coop, hipDeviceAttributeCooperativeLaunch, 0);

    bool launched = false;
    if (coop) {
        int maxActive = 0;
        hipError_t oe = hipOccupancyMaxActiveBlocksPerMultiprocessor(
            &maxActive, (const void*)fused_kernel, 256, 0);
        int ncu = 0;
        hipDeviceGetAttribute(&ncu, hipDeviceAttributeMultiprocessorCount, 0);
        if (oe == hipSuccess && maxActive >= 1 && ncu >= 1) {
            long long cap = (long long)ncu * maxActive;  // strict co-residency
            int nb = (int)(cap > 2048 ? 2048 : cap);
            if (nb >= 1024) {   // guarantees <= MAXC chunks per block
                void* args[] = {(void*)&query, (void*)&key, (void*)&w_q,
                                (void*)&b_q,   (void*)&w_k, (void*)&u,
                                (void*)&att,   (void*)&out, (void*)&nb};
                hipError_t le = hipLaunchCooperativeKernel(
                    (const void*)fused_kernel, dim3(nb), dim3(256), args, 0,
                    stream);
                launched = (le == hipSuccess);
            }
        }
    }

    if (!launched) {
        hipLaunchKernelGGL(colsum_kernel, dim3(BSZ + CHUNKS), dim3(256), 0,
                           stream, query, key, w_q, b_q, w_k, partial, u, amax);
        hipLaunchKernelGGL(att_kernel, dim3(NKEY), dim3(256), 0, stream,
                           partial, u, amax);
        hipLaunchKernelGGL(gather_kernel, dim3(512, BSZ), dim3(256), 0, stream,
                           key, amax, out);
    }
}